// Round 13
// baseline (412.353 us; speedup 1.0000x reference)
//
#include <hip/hip_runtime.h>
#include <math.h>

#define TPB 256
#define SCAN_T 256
#define SCAN_I 4
#define SCAN_CHUNK 1024  // SCAN_T * SCAN_I

typedef __attribute__((ext_vector_type(8))) short bf16x8;
typedef __attribute__((ext_vector_type(16))) float f32x16;

static __device__ __forceinline__ short f2bf(float a) {
  unsigned ua = __builtin_bit_cast(unsigned, a);
  ua = (ua + 0x7fffu + ((ua >> 16) & 1u)) >> 16;
  return (short)ua;
}
static __device__ __forceinline__ unsigned f2bf_pack(float a, float b) {
  unsigned ua = __builtin_bit_cast(unsigned, a);
  unsigned ub = __builtin_bit_cast(unsigned, b);
  ua = (ua + 0x7fffu + ((ua >> 16) & 1u)) >> 16;
  ub = (ub + 0x7fffu + ((ub >> 16) & 1u)) >> 16;
  return ua | (ub << 16);
}
static __device__ __forceinline__ float bflo(unsigned u) {
  return __builtin_bit_cast(float, u << 16);
}
static __device__ __forceinline__ float bfhi(unsigned u) {
  return __builtin_bit_cast(float, u & 0xffff0000u);
}

// ---------------- CSR build ----------------
__global__ void k_zero_int(int* __restrict__ p, int n) {
  int t = blockIdx.x * TPB + threadIdx.x;
  if (t < n) p[t] = 0;
}

__global__ void k_hist(const int* __restrict__ dst, int* __restrict__ deg, int E) {
  int t = blockIdx.x * TPB + threadIdx.x;
  if (t < E) atomicAdd(&deg[dst[t]], 1);
}

// per-block exclusive scan of deg -> loc, block sums -> bsum; dinv = rsqrt(deg+1); xs = dinv*x
__global__ __launch_bounds__(SCAN_T) void k_scan_local(const int* __restrict__ deg,
                                                       int* __restrict__ loc,
                                                       int* __restrict__ bsum,
                                                       float* __restrict__ dinv,
                                                       const float4* __restrict__ x4,
                                                       float4* __restrict__ xs, int N) {
  __shared__ int s[SCAN_T];
  int b = blockIdx.x, t = threadIdx.x;
  int base = b * SCAN_CHUNK + t * SCAN_I;
  int v[SCAN_I];
  int sum = 0;
#pragma unroll
  for (int u = 0; u < SCAN_I; u++) {
    int x = (base + u < N) ? deg[base + u] : 0;
    if (base + u < N) {
      float dv = rsqrtf((float)x + 1.0f);
      dinv[base + u] = dv;
      float4 xv = x4[base + u];
      xs[base + u] = make_float4(xv.x * dv, xv.y * dv, xv.z * dv, xv.w * dv);
    }
    v[u] = sum;
    sum += x;
  }
  s[t] = sum;
  __syncthreads();
#pragma unroll
  for (int off = 1; off < SCAN_T; off <<= 1) {
    int x = (t >= off) ? s[t - off] : 0;
    __syncthreads();
    s[t] += x;
    __syncthreads();
  }
  int excl = (t == 0) ? 0 : s[t - 1];
#pragma unroll
  for (int u = 0; u < SCAN_I; u++)
    if (base + u < N) loc[base + u] = v[u] + excl;
  if (t == SCAN_T - 1) bsum[b] = s[t];
}

// parallel exclusive scan of bsum (nb <= 128) with one wave
__global__ void k_scan_block(int* __restrict__ bsum, int nb) {
  int t = threadIdx.x;  // 0..63
  int i0 = 2 * t, i1 = 2 * t + 1;
  int a = (i0 < nb) ? bsum[i0] : 0;
  int b = (i1 < nb) ? bsum[i1] : 0;
  int s = a + b;
#pragma unroll
  for (int off = 1; off < 64; off <<= 1) {
    int u = __shfl_up(s, off, 64);
    if (t >= off) s += u;
  }
  int excl = s - (a + b);  // exclusive prefix of this pair
  if (i0 < nb) bsum[i0] = excl;
  if (i1 < nb) bsum[i1] = excl + a;
}

__global__ void k_scan_add(int* __restrict__ rowoff, const int* __restrict__ bsum,
                           int* __restrict__ cursor, int N) {
  int t = blockIdx.x * TPB + threadIdx.x;
  if (t >= N) return;
  int ro = rowoff[t] + bsum[t / SCAN_CHUNK];
  rowoff[t] = ro;
  cursor[t] = ro;
}

// slots[pos]=src; epair[pos]=(eid, dst)   (dst-sorted position order)
__global__ void k_fill_slots(const int* __restrict__ src, const int* __restrict__ dst,
                             int* __restrict__ cursor, int* __restrict__ slots,
                             int2* __restrict__ epair, int E) {
  int e = blockIdx.x * TPB + threadIdx.x;
  if (e >= E) return;
  int d = dst[e];
  int pos = atomicAdd(&cursor[d], 1);
  slots[pos] = src[e];
  epair[pos] = make_int2(e, d);
}

// ---------------- fused GCN layer 1: h1[n] = relu(dinv*( (xs[n]+sum xs[src]) @ W1 ) + b1) ----------------
__global__ __launch_bounds__(256) void k_agg1(const float4* __restrict__ xs,
                                              const int* __restrict__ rowoff,
                                              const int* __restrict__ deg,
                                              const int* __restrict__ slots,
                                              const float* __restrict__ dinv,
                                              const float* __restrict__ W1,
                                              const float* __restrict__ b1,
                                              unsigned* __restrict__ h1, int N) {
  int u = threadIdx.x & 15;  // lane-in-group; owns cols 8u..8u+7
  float w[4][8];
  float bb[8];
#pragma unroll
  for (int k = 0; k < 4; k++)
#pragma unroll
    for (int c = 0; c < 8; c++) w[k][c] = W1[k * 128 + u * 8 + c];
#pragma unroll
  for (int c = 0; c < 8; c++) bb[c] = b1[u * 8 + c];

  int g0 = (blockIdx.x * TPB + threadIdx.x) >> 4;
  int gstride = (gridDim.x * TPB) >> 4;
  for (int n = g0; n < N; n += gstride) {
    int start = rowoff[n], d = deg[n];
    float4 acc = make_float4(0.f, 0.f, 0.f, 0.f);
    for (int j = u; j < d; j += 16) {
      float4 v = xs[slots[start + j]];
      acc.x += v.x;
      acc.y += v.y;
      acc.z += v.z;
      acc.w += v.w;
    }
#pragma unroll
    for (int off = 8; off >= 1; off >>= 1) {
      acc.x += __shfl_xor(acc.x, off, 16);
      acc.y += __shfl_xor(acc.y, off, 16);
      acc.z += __shfl_xor(acc.z, off, 16);
      acc.w += __shfl_xor(acc.w, off, 16);
    }
    float4 xv = xs[n];  // self-loop term
    acc.x += xv.x;
    acc.y += xv.y;
    acc.z += xv.z;
    acc.w += xv.w;
    float sc = dinv[n];
    uint4 o;
    unsigned* op = (unsigned*)&o;
#pragma unroll
    for (int c2 = 0; c2 < 4; c2++) {
      int c0 = 2 * c2, c1 = 2 * c2 + 1;
      float r0 = fmaf(acc.x, w[0][c0],
                      fmaf(acc.y, w[1][c0], fmaf(acc.z, w[2][c0], acc.w * w[3][c0])));
      float r1 = fmaf(acc.x, w[0][c1],
                      fmaf(acc.y, w[1][c1], fmaf(acc.z, w[2][c1], acc.w * w[3][c1])));
      r0 = fmaxf(fmaf(r0, sc, bb[c0]), 0.f);
      r1 = fmaxf(fmaf(r1, sc, bb[c1]), 0.f);
      op[c2] = f2bf_pack(r0, r1);
    }
    *(uint4*)&h1[(size_t)n * 64 + u * 4] = o;
  }
}

// ---------------- CSR aggregate: 16 lanes/node, uint4 loads, masked 8-wide parallel gather ----------------
template <bool RELU>
__global__ void k_agg(const unsigned* __restrict__ ts, const int* __restrict__ rowoff,
                      const int* __restrict__ deg, const int* __restrict__ slots,
                      const float* __restrict__ dinv, const float* __restrict__ bias,
                      unsigned* __restrict__ hout, int N) {
  int t = blockIdx.x * TPB + threadIdx.x;
  int n = t >> 4;  // 16 lanes per node
  if (n >= N) return;
  int q = (t & 15) << 2;  // uint index, 16B per lane: cols 2q..2q+7
  uint4 sv = *(const uint4*)&ts[(size_t)n * 64 + q];
  float a0 = bflo(sv.x), a1 = bfhi(sv.x), a2 = bflo(sv.y), a3 = bfhi(sv.y);
  float a4 = bflo(sv.z), a5 = bfhi(sv.z), a6 = bflo(sv.w), a7 = bfhi(sv.w);
  int start = rowoff[n], d = deg[n];
  for (int j0 = 0; j0 < d; j0 += 8) {
    int sl[8];
#pragma unroll
    for (int u = 0; u < 8; u++) {
      int jj = j0 + u;
      sl[u] = (jj < d) ? slots[start + jj] : -1;
    }
    uint4 v[8];
#pragma unroll
    for (int u = 0; u < 8; u++)
      v[u] = (sl[u] >= 0) ? *(const uint4*)&ts[(size_t)sl[u] * 64 + q]
                          : make_uint4(0u, 0u, 0u, 0u);
#pragma unroll
    for (int u = 0; u < 8; u++) {
      a0 += bflo(v[u].x);
      a1 += bfhi(v[u].x);
      a2 += bflo(v[u].y);
      a3 += bfhi(v[u].y);
      a4 += bflo(v[u].z);
      a5 += bfhi(v[u].z);
      a6 += bflo(v[u].w);
      a7 += bfhi(v[u].w);
    }
  }
  float sc = dinv[n];
  int col = q << 1;
  float4 b0 = *(const float4*)&bias[col];
  float4 b1 = *(const float4*)&bias[col + 4];
  a0 = a0 * sc + b0.x;
  a1 = a1 * sc + b0.y;
  a2 = a2 * sc + b0.z;
  a3 = a3 * sc + b0.w;
  a4 = a4 * sc + b1.x;
  a5 = a5 * sc + b1.y;
  a6 = a6 * sc + b1.z;
  a7 = a7 * sc + b1.w;
  if (RELU) {
    a0 = fmaxf(a0, 0.f);
    a1 = fmaxf(a1, 0.f);
    a2 = fmaxf(a2, 0.f);
    a3 = fmaxf(a3, 0.f);
    a4 = fmaxf(a4, 0.f);
    a5 = fmaxf(a5, 0.f);
    a6 = fmaxf(a6, 0.f);
    a7 = fmaxf(a7, 0.f);
  }
  uint4 p;
  p.x = f2bf_pack(a0, a1);
  p.y = f2bf_pack(a2, a3);
  p.z = f2bf_pack(a4, a5);
  p.w = f2bf_pack(a6, a7);
  *(uint4*)&hout[(size_t)n * 64 + q] = p;
}

// ---------------- persistent MFMA GEMM: out = dinv[n] * (A[n]@W), bf16 in/out ----------------
template <bool BIAS, bool DINV>
__global__ __launch_bounds__(256, 2) void k_gemm_bf(const unsigned* __restrict__ A,
                                                    const float* __restrict__ W,
                                                    const float* __restrict__ bias,
                                                    const float* __restrict__ dinv,
                                                    unsigned* __restrict__ out, int N) {
  __shared__ unsigned sA[64 * 64];  // 64 rows x 128 bf16, XOR-swizzled
  __shared__ float sDinv[64];
  int tid = threadIdx.x;
  int wv = tid >> 6, lane = tid & 63;
  int rg = wv >> 1, ch = wv & 1;
  int l31 = lane & 31, h = lane >> 5;

  bf16x8 wf[2][8];
  float bcol[2];
#pragma unroll
  for (int t = 0; t < 2; t++) {
    int col = ch * 64 + 2 * l31 + t;
#pragma unroll
    for (int kk = 0; kk < 8; kk++) {
      int kb = kk * 16 + h * 8;
      bf16x8 v;
#pragma unroll
      for (int u = 0; u < 8; u++) v[u] = f2bf(W[(kb + u) * 128 + col]);
      wf[t][kk] = v;
    }
    bcol[t] = BIAS ? bias[col] : 0.f;
  }

  int ntiles = (N + 63) >> 6;
  for (int tile = blockIdx.x; tile < ntiles; tile += gridDim.x) {
    __syncthreads();
    int row0 = tile << 6;
    for (int idx = tid; idx < 1024; idx += 256) {
      int r = idx >> 4, c4 = idx & 15;
      int n = row0 + r;
      uint4 v = (n < N) ? ((const uint4*)A)[(size_t)n * 16 + c4] : make_uint4(0, 0, 0, 0);
      *(uint4*)&sA[r * 64 + ((c4 * 4) ^ ((r & 15) << 2))] = v;
    }
    if (DINV && tid < 64) sDinv[tid] = (row0 + tid < N) ? dinv[row0 + tid] : 0.f;
    __syncthreads();

    int arow = rg * 32 + l31;
    const char* abase = (const char*)sA + arow * 256;
    int swz = (arow & 15) << 4;
    f32x16 acc[2];
#pragma unroll
    for (int t = 0; t < 2; t++) {
#pragma unroll
      for (int r = 0; r < 16; r++) acc[t][r] = 0.f;
    }
#pragma unroll
    for (int kk = 0; kk < 8; kk++) {
      bf16x8 a = *(const bf16x8*)(abase + ((kk * 32 + h * 16) ^ swz));
      acc[0] = __builtin_amdgcn_mfma_f32_32x32x16_bf16(a, wf[0][kk], acc[0], 0, 0, 0);
      acc[1] = __builtin_amdgcn_mfma_f32_32x32x16_bf16(a, wf[1][kk], acc[1], 0, 0, 0);
    }
#pragma unroll
    for (int r = 0; r < 16; r++) {
      int drow = (r & 3) + 8 * (r >> 2) + 4 * h;
      int n = row0 + rg * 32 + drow;
      if (n < N) {
        float v0 = acc[0][r] + bcol[0];
        float v1 = acc[1][r] + bcol[1];
        if (DINV) {
          float s = sDinv[rg * 32 + drow];
          v0 *= s;
          v1 *= s;
        }
        out[(size_t)n * 64 + ch * 32 + l31] = f2bf_pack(v0, v1);
      }
    }
  }
}

// ---------------- fused dual GEMM: a_s = A@Wm1[0:128]+bm1 ; a_d = A@Wm1[128:256] ----------------
__global__ __launch_bounds__(512, 2) void k_gemm_dual(const unsigned* __restrict__ A,
                                                      const float* __restrict__ Wm1,
                                                      const float* __restrict__ bm1,
                                                      unsigned* __restrict__ out_s,
                                                      unsigned* __restrict__ out_d, int N) {
  __shared__ unsigned sA[64 * 64];
  int tid = threadIdx.x;
  int wv = tid >> 6, lane = tid & 63;
  int part = wv >> 2;  // 0: a_s, 1: a_d
  int w4 = wv & 3;
  int rg = w4 >> 1, ch = w4 & 1;
  int l31 = lane & 31, h = lane >> 5;
  const float* W = Wm1 + (size_t)part * 128 * 128;
  unsigned* outp = part ? out_d : out_s;

  bf16x8 wf[2][8];
  float bcol[2];
#pragma unroll
  for (int t = 0; t < 2; t++) {
    int col = ch * 64 + 2 * l31 + t;
#pragma unroll
    for (int kk = 0; kk < 8; kk++) {
      int kb = kk * 16 + h * 8;
      bf16x8 v;
#pragma unroll
      for (int u = 0; u < 8; u++) v[u] = f2bf(W[(kb + u) * 128 + col]);
      wf[t][kk] = v;
    }
    bcol[t] = part ? 0.f : bm1[col];
  }

  int ntiles = (N + 63) >> 6;
  for (int tile = blockIdx.x; tile < ntiles; tile += gridDim.x) {
    __syncthreads();
    int row0 = tile << 6;
    for (int idx = tid; idx < 1024; idx += 512) {
      int r = idx >> 4, c4 = idx & 15;
      int n = row0 + r;
      uint4 v = (n < N) ? ((const uint4*)A)[(size_t)n * 16 + c4] : make_uint4(0, 0, 0, 0);
      *(uint4*)&sA[r * 64 + ((c4 * 4) ^ ((r & 15) << 2))] = v;
    }
    __syncthreads();

    int arow = rg * 32 + l31;
    const char* abase = (const char*)sA + arow * 256;
    int swz = (arow & 15) << 4;
    f32x16 acc[2];
#pragma unroll
    for (int t = 0; t < 2; t++) {
#pragma unroll
      for (int r = 0; r < 16; r++) acc[t][r] = 0.f;
    }
#pragma unroll
    for (int kk = 0; kk < 8; kk++) {
      bf16x8 a = *(const bf16x8*)(abase + ((kk * 32 + h * 16) ^ swz));
      acc[0] = __builtin_amdgcn_mfma_f32_32x32x16_bf16(a, wf[0][kk], acc[0], 0, 0, 0);
      acc[1] = __builtin_amdgcn_mfma_f32_32x32x16_bf16(a, wf[1][kk], acc[1], 0, 0, 0);
    }
#pragma unroll
    for (int r = 0; r < 16; r++) {
      int drow = (r & 3) + 8 * (r >> 2) + 4 * h;
      int n = row0 + rg * 32 + drow;
      if (n < N) {
        float v0 = acc[0][r] + bcol[0];
        float v1 = acc[1][r] + bcol[1];
        outp[(size_t)n * 64 + ch * 32 + l31] = f2bf_pack(v0, v1);
      }
    }
  }
}

// ---------------- fused edge MLP: dst-sorted + cross-tile a_s prefetch, 3 waves/EU ----------------
// a_s gathers are HBM-random (the measured 127MB overfetch); issue them for tile t+1
// right after sZ1(t) is built so they ride under Phase B MFMA + epilogue.
// a_d gathers are dst-sorted (cache-friendly) -> gathered just-in-time.
__global__ __launch_bounds__(256, 3) void k_edge_mlp(
    const unsigned* __restrict__ a_s, const unsigned* __restrict__ a_d,
    const float* __restrict__ eattr, const int* __restrict__ slots,
    const int2* __restrict__ epair, const float* __restrict__ We,
    const float* __restrict__ Wm2, const float* __restrict__ bm2,
    const float* __restrict__ Wm3, const float* __restrict__ bm3,
    float* __restrict__ out, int E) {
  __shared__ unsigned sZ1[64 * 64];  // 64 rows x 128 bf16, XOR-swizzled
  __shared__ float sEa[2][64][5];
  __shared__ int sSrc[2][64], sDst[2][64], sEid[2][64];
  __shared__ float sP[64][2];

  int tid = threadIdx.x;
  int wv = tid >> 6;
  int lane = tid & 63;
  int rg = wv >> 1;
  int ch = wv & 1;
  int l31 = lane & 31;
  int h = lane >> 5;

  bf16x8 bfr[2][8];
#pragma unroll
  for (int t = 0; t < 2; t++) {
    int col = ch * 64 + t * 32 + l31;
#pragma unroll
    for (int kk = 0; kk < 8; kk++) {
      int kb = kk * 16 + h * 8;
      bf16x8 v;
#pragma unroll
      for (int u = 0; u < 8; u++) v[u] = f2bf(Wm2[(kb + u) * 128 + col]);
      bfr[t][kk] = v;
    }
  }
  float wm3c[2], bm2c[2];
#pragma unroll
  for (int t = 0; t < 2; t++) {
    int col = ch * 64 + t * 32 + l31;
    wm3c[t] = Wm3[col];
    bm2c[t] = bm2[col];
  }
  float bm3v = bm3[0];
  float2 we[5];
#pragma unroll
  for (int j = 0; j < 5; j++) we[j] = *(const float2*)(We + j * 128 + 2 * lane);

  int ntiles = (E + 63) >> 6;

  auto stage = [&](int t, int b) {
    bool tv = t < ntiles;
    if (tid < 64) {
      int p = (t << 6) + tid;
      bool v = tv && (p < E);
      int2 ed = v ? epair[p] : make_int2(0, 0);
      sSrc[b][tid] = v ? slots[p] : 0;
      sDst[b][tid] = ed.y;
      sEid[b][tid] = ed.x;
    }
    for (int idx = tid; idx < 320; idx += 256) {
      int r = idx / 5, j = idx - r * 5;
      int p = (t << 6) + r;
      bool v = tv && (p < E);
      int e = v ? epair[p].x : 0;
      sEa[b][r][j] = v ? eattr[(size_t)e * 5 + j] : 0.f;
    }
  };

  int tile0 = blockIdx.x;
  if (tile0 >= ntiles) return;

  // prologue: stage tile0 + issue its a_s gathers
  stage(tile0, 0);
  __syncthreads();
  unsigned ua[16];
#pragma unroll
  for (int i = 0; i < 16; i++)
    ua[i] = a_s[(size_t)sSrc[0][wv * 16 + i] * 64 + lane];

  int c = 0;
  for (int tile = tile0; tile < ntiles; tile += gridDim.x, c ^= 1) {
    // stage NEXT tile's indices/eattr into the other buffer
    stage(tile + gridDim.x, c ^ 1);

    // gather a_d just-in-time (dst-sorted -> same-address runs, L1/L2 hits)
    unsigned ud[16];
#pragma unroll
    for (int i = 0; i < 16; i++)
      ud[i] = a_d[(size_t)sDst[c][wv * 16 + i] * 64 + lane];

    // Phase A: z1 from prefetched ua + ud -> sZ1
#pragma unroll
    for (int i = 0; i < 16; i++) {
      int r = wv * 16 + i;
      float v0 = bflo(ua[i]) + bflo(ud[i]);
      float v1 = bfhi(ua[i]) + bfhi(ud[i]);
#pragma unroll
      for (int j = 0; j < 5; j++) {
        float ea = sEa[c][r][j];
        v0 = fmaf(ea, we[j].x, v0);
        v1 = fmaf(ea, we[j].y, v1);
      }
      v0 = fmaxf(v0, 0.f);
      v1 = fmaxf(v1, 0.f);
      sZ1[r * 64 + (lane ^ ((r & 15) << 2))] = f2bf_pack(v0, v1);
    }
    __syncthreads();  // sZ1 ready; next-tile indices staged

    // issue a_s gathers for NEXT tile: land under Phase B + epilogue
    if (tile + gridDim.x < ntiles) {
#pragma unroll
      for (int i = 0; i < 16; i++)
        ua[i] = a_s[(size_t)sSrc[c ^ 1][wv * 16 + i] * 64 + lane];
    }

    // Phase B: C[32 rows][64 cols] via mfma_f32_32x32x16_bf16
    int arow = rg * 32 + l31;
    const char* abase = (const char*)sZ1 + arow * 256;
    int swz = (arow & 15) << 4;
    float p16[16];
#pragma unroll
    for (int r = 0; r < 16; r++) p16[r] = 0.f;
#pragma unroll
    for (int t = 0; t < 2; t++) {
      f32x16 acc;
#pragma unroll
      for (int r = 0; r < 16; r++) acc[r] = 0.f;
#pragma unroll
      for (int kk = 0; kk < 8; kk++) {
        bf16x8 a = *(const bf16x8*)(abase + ((kk * 32 + h * 16) ^ swz));
        acc = __builtin_amdgcn_mfma_f32_32x32x16_bf16(a, bfr[t][kk], acc, 0, 0, 0);
      }
#pragma unroll
      for (int r = 0; r < 16; r++) {
        float z2 = fmaxf(acc[r] + bm2c[t], 0.f);
        p16[r] = fmaf(z2, wm3c[t], p16[r]);
      }
    }
#pragma unroll
    for (int r = 0; r < 16; r++) {
      float p = p16[r];
#pragma unroll
      for (int off = 16; off >= 1; off >>= 1) p += __shfl_xor(p, off, 32);
      if (l31 == 0) {
        int row = (r & 3) + 8 * (r >> 2) + 4 * h;
        sP[rg * 32 + row][ch] = p;
      }
    }
    __syncthreads();

    // epilogue: scatter sigmoid to original edge ids
    if (tid < 64) {
      int p = (tile << 6) + tid;
      if (p < E) {
        float pv = sP[tid][0] + sP[tid][1] + bm3v;
        out[sEid[c][tid]] = 1.f / (1.f + __expf(-pv));
      }
    }
    __syncthreads();  // protect sZ1/sP/buf[c] before next iteration
  }
}

// ---------------- launch ----------------
extern "C" void kernel_launch(void* const* d_in, const int* in_sizes, int n_in,
                              void* d_out, int out_size, void* d_ws, size_t ws_size,
                              hipStream_t stream) {
  const float* x = (const float*)d_in[0];
  const float* eattr = (const float*)d_in[1];
  const float* W1 = (const float*)d_in[2];
  const float* b1 = (const float*)d_in[3];
  const float* W2 = (const float*)d_in[4];
  const float* b2 = (const float*)d_in[5];
  const float* Wm1 = (const float*)d_in[6];
  const float* bm1 = (const float*)d_in[7];
  const float* Wm2 = (const float*)d_in[8];
  const float* bm2 = (const float*)d_in[9];
  const float* Wm3 = (const float*)d_in[10];
  const float* bm3 = (const float*)d_in[11];
  const int* ei = (const int*)d_in[12];
  int N = in_sizes[0] / 4;
  int E = in_sizes[12] / 2;
  const int* src = ei;
  const int* dst = ei + E;
  float* out = (float*)d_out;

  size_t npad = (size_t)((N + 63) & ~63);
  float* dinv = (float*)d_ws;
  float4* xs = (float4*)(dinv + npad);          // npad float4
  unsigned* U1 = (unsigned*)(xs + npad);        // ts2
  unsigned* U2 = U1 + (size_t)N * 64;           // h1, later a_s
  unsigned* U3 = U2 + (size_t)N * 64;           // h2
  unsigned* U4 = U3 + (size_t)N * 64;           // a_d
  int* degi = (int*)(U4 + (size_t)N * 64);
  int* rowoff = degi + npad;
  int* cursor = rowoff + npad;
  int* bsum = cursor + npad;  // 256 slots
  int* slots = bsum + 256;
  int2* epair = (int2*)(slots + ((E + 1) & ~1));

  int gN = (N + TPB - 1) / TPB;
  int gE = (E + TPB - 1) / TPB;
  int gN16 = (N * 16 + TPB - 1) / TPB;
  int nb1 = (N + SCAN_CHUNK - 1) / SCAN_CHUNK;

  // CSR build (dst-sorted adjacency) + dinv + xs
  k_zero_int<<<gN, TPB, 0, stream>>>(degi, N);
  k_hist<<<gE, TPB, 0, stream>>>(dst, degi, E);
  k_scan_local<<<nb1, SCAN_T, 0, stream>>>(degi, rowoff, bsum, dinv, (const float4*)x, xs, N);
  k_scan_block<<<1, 64, 0, stream>>>(bsum, nb1);
  k_scan_add<<<gN, TPB, 0, stream>>>(rowoff, bsum, cursor, N);
  k_fill_slots<<<gE, TPB, 0, stream>>>(src, dst, cursor, slots, epair, E);

  // GCN layer 1 (fused transform+aggregate via linearity): h1 in U2
  k_agg1<<<2048, TPB, 0, stream>>>(xs, rowoff, degi, slots, dinv, W1, b1, U2, N);

  // GCN layer 2: ts2 = dinv*(h1@W2) (U1) -> h2 (U3)
  k_gemm_bf<false, true><<<512, TPB, 0, stream>>>(U2, W2, nullptr, dinv, U1, N);
  k_agg<false><<<gN16, TPB, 0, stream>>>(U1, rowoff, degi, slots, dinv, b2, U3, N);

  // Edge classifier: a_s (U2), a_d (U4) in one fused kernel
  k_gemm_dual<<<512, 512, 0, stream>>>(U3, Wm1, bm1, U2, U4, N);
  k_edge_mlp<<<2048, TPB, 0, stream>>>(U2, U4, eattr, slots, epair,
                                       Wm1 + 256 * 128, Wm2, bm2, Wm3, bm3, out, E);
}

// Round 14
// 281.521 us; speedup vs baseline: 1.4647x; 1.4647x over previous
//
#include <hip/hip_runtime.h>
#include <math.h>

#define TPB 256
#define SCAN_T 256
#define SCAN_I 4
#define SCAN_CHUNK 1024  // SCAN_T * SCAN_I

typedef __attribute__((ext_vector_type(8))) short bf16x8;
typedef __attribute__((ext_vector_type(16))) float f32x16;

static __device__ __forceinline__ short f2bf(float a) {
  unsigned ua = __builtin_bit_cast(unsigned, a);
  ua = (ua + 0x7fffu + ((ua >> 16) & 1u)) >> 16;
  return (short)ua;
}
static __device__ __forceinline__ unsigned f2bf_pack(float a, float b) {
  unsigned ua = __builtin_bit_cast(unsigned, a);
  unsigned ub = __builtin_bit_cast(unsigned, b);
  ua = (ua + 0x7fffu + ((ua >> 16) & 1u)) >> 16;
  ub = (ub + 0x7fffu + ((ub >> 16) & 1u)) >> 16;
  return ua | (ub << 16);
}
static __device__ __forceinline__ float bflo(unsigned u) {
  return __builtin_bit_cast(float, u << 16);
}
static __device__ __forceinline__ float bfhi(unsigned u) {
  return __builtin_bit_cast(float, u & 0xffff0000u);
}

// ---------------- CSR build ----------------
__global__ void k_zero_int(int* __restrict__ p, int n) {
  int t = blockIdx.x * TPB + threadIdx.x;
  if (t < n) p[t] = 0;
}

__global__ void k_hist(const int* __restrict__ dst, int* __restrict__ deg, int E) {
  int t = blockIdx.x * TPB + threadIdx.x;
  if (t < E) atomicAdd(&deg[dst[t]], 1);
}

// per-block exclusive scan of deg -> loc, block sums -> bsum; dinv = rsqrt(deg+1); xs = dinv*x
__global__ __launch_bounds__(SCAN_T) void k_scan_local(const int* __restrict__ deg,
                                                       int* __restrict__ loc,
                                                       int* __restrict__ bsum,
                                                       float* __restrict__ dinv,
                                                       const float4* __restrict__ x4,
                                                       float4* __restrict__ xs, int N) {
  __shared__ int s[SCAN_T];
  int b = blockIdx.x, t = threadIdx.x;
  int base = b * SCAN_CHUNK + t * SCAN_I;
  int v[SCAN_I];
  int sum = 0;
#pragma unroll
  for (int u = 0; u < SCAN_I; u++) {
    int x = (base + u < N) ? deg[base + u] : 0;
    if (base + u < N) {
      float dv = rsqrtf((float)x + 1.0f);
      dinv[base + u] = dv;
      float4 xv = x4[base + u];
      xs[base + u] = make_float4(xv.x * dv, xv.y * dv, xv.z * dv, xv.w * dv);
    }
    v[u] = sum;
    sum += x;
  }
  s[t] = sum;
  __syncthreads();
#pragma unroll
  for (int off = 1; off < SCAN_T; off <<= 1) {
    int x = (t >= off) ? s[t - off] : 0;
    __syncthreads();
    s[t] += x;
    __syncthreads();
  }
  int excl = (t == 0) ? 0 : s[t - 1];
#pragma unroll
  for (int u = 0; u < SCAN_I; u++)
    if (base + u < N) loc[base + u] = v[u] + excl;
  if (t == SCAN_T - 1) bsum[b] = s[t];
}

// parallel exclusive scan of bsum (nb <= 128) with one wave
__global__ void k_scan_block(int* __restrict__ bsum, int nb) {
  int t = threadIdx.x;  // 0..63
  int i0 = 2 * t, i1 = 2 * t + 1;
  int a = (i0 < nb) ? bsum[i0] : 0;
  int b = (i1 < nb) ? bsum[i1] : 0;
  int s = a + b;
#pragma unroll
  for (int off = 1; off < 64; off <<= 1) {
    int u = __shfl_up(s, off, 64);
    if (t >= off) s += u;
  }
  int excl = s - (a + b);  // exclusive prefix of this pair
  if (i0 < nb) bsum[i0] = excl;
  if (i1 < nb) bsum[i1] = excl + a;
}

__global__ void k_scan_add(int* __restrict__ rowoff, const int* __restrict__ bsum,
                           int* __restrict__ cursor, int N) {
  int t = blockIdx.x * TPB + threadIdx.x;
  if (t >= N) return;
  int ro = rowoff[t] + bsum[t / SCAN_CHUNK];
  rowoff[t] = ro;
  cursor[t] = ro;
}

// slots[pos]=src; epair[pos]=(eid, dst)   (dst-sorted position order)
__global__ void k_fill_slots(const int* __restrict__ src, const int* __restrict__ dst,
                             int* __restrict__ cursor, int* __restrict__ slots,
                             int2* __restrict__ epair, int E) {
  int e = blockIdx.x * TPB + threadIdx.x;
  if (e >= E) return;
  int d = dst[e];
  int pos = atomicAdd(&cursor[d], 1);
  slots[pos] = src[e];
  epair[pos] = make_int2(e, d);
}

// ---------------- fused GCN layer 1: h1[n] = relu(dinv*( (xs[n]+sum xs[src]) @ W1 ) + b1) ----------------
__global__ __launch_bounds__(256) void k_agg1(const float4* __restrict__ xs,
                                              const int* __restrict__ rowoff,
                                              const int* __restrict__ deg,
                                              const int* __restrict__ slots,
                                              const float* __restrict__ dinv,
                                              const float* __restrict__ W1,
                                              const float* __restrict__ b1,
                                              unsigned* __restrict__ h1, int N) {
  int u = threadIdx.x & 15;  // lane-in-group; owns cols 8u..8u+7
  float w[4][8];
  float bb[8];
#pragma unroll
  for (int k = 0; k < 4; k++)
#pragma unroll
    for (int c = 0; c < 8; c++) w[k][c] = W1[k * 128 + u * 8 + c];
#pragma unroll
  for (int c = 0; c < 8; c++) bb[c] = b1[u * 8 + c];

  int g0 = (blockIdx.x * TPB + threadIdx.x) >> 4;
  int gstride = (gridDim.x * TPB) >> 4;
  for (int n = g0; n < N; n += gstride) {
    int start = rowoff[n], d = deg[n];
    float4 acc = make_float4(0.f, 0.f, 0.f, 0.f);
    for (int j = u; j < d; j += 16) {
      float4 v = xs[slots[start + j]];
      acc.x += v.x;
      acc.y += v.y;
      acc.z += v.z;
      acc.w += v.w;
    }
#pragma unroll
    for (int off = 8; off >= 1; off >>= 1) {
      acc.x += __shfl_xor(acc.x, off, 16);
      acc.y += __shfl_xor(acc.y, off, 16);
      acc.z += __shfl_xor(acc.z, off, 16);
      acc.w += __shfl_xor(acc.w, off, 16);
    }
    float4 xv = xs[n];  // self-loop term
    acc.x += xv.x;
    acc.y += xv.y;
    acc.z += xv.z;
    acc.w += xv.w;
    float sc = dinv[n];
    uint4 o;
    unsigned* op = (unsigned*)&o;
#pragma unroll
    for (int c2 = 0; c2 < 4; c2++) {
      int c0 = 2 * c2, c1 = 2 * c2 + 1;
      float r0 = fmaf(acc.x, w[0][c0],
                      fmaf(acc.y, w[1][c0], fmaf(acc.z, w[2][c0], acc.w * w[3][c0])));
      float r1 = fmaf(acc.x, w[0][c1],
                      fmaf(acc.y, w[1][c1], fmaf(acc.z, w[2][c1], acc.w * w[3][c1])));
      r0 = fmaxf(fmaf(r0, sc, bb[c0]), 0.f);
      r1 = fmaxf(fmaf(r1, sc, bb[c1]), 0.f);
      op[c2] = f2bf_pack(r0, r1);
    }
    *(uint4*)&h1[(size_t)n * 64 + u * 4] = o;
  }
}

// ---------------- CSR aggregate: 16 lanes/node, uint4 loads, masked 8-wide parallel gather ----------------
template <bool RELU>
__global__ void k_agg(const unsigned* __restrict__ ts, const int* __restrict__ rowoff,
                      const int* __restrict__ deg, const int* __restrict__ slots,
                      const float* __restrict__ dinv, const float* __restrict__ bias,
                      unsigned* __restrict__ hout, int N) {
  int t = blockIdx.x * TPB + threadIdx.x;
  int n = t >> 4;  // 16 lanes per node
  if (n >= N) return;
  int q = (t & 15) << 2;  // uint index, 16B per lane: cols 2q..2q+7
  uint4 sv = *(const uint4*)&ts[(size_t)n * 64 + q];
  float a0 = bflo(sv.x), a1 = bfhi(sv.x), a2 = bflo(sv.y), a3 = bfhi(sv.y);
  float a4 = bflo(sv.z), a5 = bfhi(sv.z), a6 = bflo(sv.w), a7 = bfhi(sv.w);
  int start = rowoff[n], d = deg[n];
  for (int j0 = 0; j0 < d; j0 += 8) {
    int sl[8];
#pragma unroll
    for (int u = 0; u < 8; u++) {
      int jj = j0 + u;
      sl[u] = (jj < d) ? slots[start + jj] : -1;
    }
    uint4 v[8];
#pragma unroll
    for (int u = 0; u < 8; u++)
      v[u] = (sl[u] >= 0) ? *(const uint4*)&ts[(size_t)sl[u] * 64 + q]
                          : make_uint4(0u, 0u, 0u, 0u);
#pragma unroll
    for (int u = 0; u < 8; u++) {
      a0 += bflo(v[u].x);
      a1 += bfhi(v[u].x);
      a2 += bflo(v[u].y);
      a3 += bfhi(v[u].y);
      a4 += bflo(v[u].z);
      a5 += bfhi(v[u].z);
      a6 += bflo(v[u].w);
      a7 += bfhi(v[u].w);
    }
  }
  float sc = dinv[n];
  int col = q << 1;
  float4 b0 = *(const float4*)&bias[col];
  float4 b1 = *(const float4*)&bias[col + 4];
  a0 = a0 * sc + b0.x;
  a1 = a1 * sc + b0.y;
  a2 = a2 * sc + b0.z;
  a3 = a3 * sc + b0.w;
  a4 = a4 * sc + b1.x;
  a5 = a5 * sc + b1.y;
  a6 = a6 * sc + b1.z;
  a7 = a7 * sc + b1.w;
  if (RELU) {
    a0 = fmaxf(a0, 0.f);
    a1 = fmaxf(a1, 0.f);
    a2 = fmaxf(a2, 0.f);
    a3 = fmaxf(a3, 0.f);
    a4 = fmaxf(a4, 0.f);
    a5 = fmaxf(a5, 0.f);
    a6 = fmaxf(a6, 0.f);
    a7 = fmaxf(a7, 0.f);
  }
  uint4 p;
  p.x = f2bf_pack(a0, a1);
  p.y = f2bf_pack(a2, a3);
  p.z = f2bf_pack(a4, a5);
  p.w = f2bf_pack(a6, a7);
  *(uint4*)&hout[(size_t)n * 64 + q] = p;
}

// ---------------- persistent MFMA GEMM: out = dinv[n] * (A[n]@W), bf16 in/out ----------------
template <bool BIAS, bool DINV>
__global__ __launch_bounds__(256, 2) void k_gemm_bf(const unsigned* __restrict__ A,
                                                    const float* __restrict__ W,
                                                    const float* __restrict__ bias,
                                                    const float* __restrict__ dinv,
                                                    unsigned* __restrict__ out, int N) {
  __shared__ unsigned sA[64 * 64];  // 64 rows x 128 bf16, XOR-swizzled
  __shared__ float sDinv[64];
  int tid = threadIdx.x;
  int wv = tid >> 6, lane = tid & 63;
  int rg = wv >> 1, ch = wv & 1;
  int l31 = lane & 31, h = lane >> 5;

  bf16x8 wf[2][8];
  float bcol[2];
#pragma unroll
  for (int t = 0; t < 2; t++) {
    int col = ch * 64 + 2 * l31 + t;
#pragma unroll
    for (int kk = 0; kk < 8; kk++) {
      int kb = kk * 16 + h * 8;
      bf16x8 v;
#pragma unroll
      for (int u = 0; u < 8; u++) v[u] = f2bf(W[(kb + u) * 128 + col]);
      wf[t][kk] = v;
    }
    bcol[t] = BIAS ? bias[col] : 0.f;
  }

  int ntiles = (N + 63) >> 6;
  for (int tile = blockIdx.x; tile < ntiles; tile += gridDim.x) {
    __syncthreads();
    int row0 = tile << 6;
    for (int idx = tid; idx < 1024; idx += 256) {
      int r = idx >> 4, c4 = idx & 15;
      int n = row0 + r;
      uint4 v = (n < N) ? ((const uint4*)A)[(size_t)n * 16 + c4] : make_uint4(0, 0, 0, 0);
      *(uint4*)&sA[r * 64 + ((c4 * 4) ^ ((r & 15) << 2))] = v;
    }
    if (DINV && tid < 64) sDinv[tid] = (row0 + tid < N) ? dinv[row0 + tid] : 0.f;
    __syncthreads();

    int arow = rg * 32 + l31;
    const char* abase = (const char*)sA + arow * 256;
    int swz = (arow & 15) << 4;
    f32x16 acc[2];
#pragma unroll
    for (int t = 0; t < 2; t++) {
#pragma unroll
      for (int r = 0; r < 16; r++) acc[t][r] = 0.f;
    }
#pragma unroll
    for (int kk = 0; kk < 8; kk++) {
      bf16x8 a = *(const bf16x8*)(abase + ((kk * 32 + h * 16) ^ swz));
      acc[0] = __builtin_amdgcn_mfma_f32_32x32x16_bf16(a, wf[0][kk], acc[0], 0, 0, 0);
      acc[1] = __builtin_amdgcn_mfma_f32_32x32x16_bf16(a, wf[1][kk], acc[1], 0, 0, 0);
    }
#pragma unroll
    for (int r = 0; r < 16; r++) {
      int drow = (r & 3) + 8 * (r >> 2) + 4 * h;
      int n = row0 + rg * 32 + drow;
      if (n < N) {
        float v0 = acc[0][r] + bcol[0];
        float v1 = acc[1][r] + bcol[1];
        if (DINV) {
          float s = sDinv[rg * 32 + drow];
          v0 *= s;
          v1 *= s;
        }
        out[(size_t)n * 64 + ch * 32 + l31] = f2bf_pack(v0, v1);
      }
    }
  }
}

// ---------------- fused dual GEMM: a_s = A@Wm1[0:128]+bm1 ; a_d = A@Wm1[128:256] ----------------
__global__ __launch_bounds__(512, 2) void k_gemm_dual(const unsigned* __restrict__ A,
                                                      const float* __restrict__ Wm1,
                                                      const float* __restrict__ bm1,
                                                      unsigned* __restrict__ out_s,
                                                      unsigned* __restrict__ out_d, int N) {
  __shared__ unsigned sA[64 * 64];
  int tid = threadIdx.x;
  int wv = tid >> 6, lane = tid & 63;
  int part = wv >> 2;  // 0: a_s, 1: a_d
  int w4 = wv & 3;
  int rg = w4 >> 1, ch = w4 & 1;
  int l31 = lane & 31, h = lane >> 5;
  const float* W = Wm1 + (size_t)part * 128 * 128;
  unsigned* outp = part ? out_d : out_s;

  bf16x8 wf[2][8];
  float bcol[2];
#pragma unroll
  for (int t = 0; t < 2; t++) {
    int col = ch * 64 + 2 * l31 + t;
#pragma unroll
    for (int kk = 0; kk < 8; kk++) {
      int kb = kk * 16 + h * 8;
      bf16x8 v;
#pragma unroll
      for (int u = 0; u < 8; u++) v[u] = f2bf(W[(kb + u) * 128 + col]);
      wf[t][kk] = v;
    }
    bcol[t] = part ? 0.f : bm1[col];
  }

  int ntiles = (N + 63) >> 6;
  for (int tile = blockIdx.x; tile < ntiles; tile += gridDim.x) {
    __syncthreads();
    int row0 = tile << 6;
    for (int idx = tid; idx < 1024; idx += 512) {
      int r = idx >> 4, c4 = idx & 15;
      int n = row0 + r;
      uint4 v = (n < N) ? ((const uint4*)A)[(size_t)n * 16 + c4] : make_uint4(0, 0, 0, 0);
      *(uint4*)&sA[r * 64 + ((c4 * 4) ^ ((r & 15) << 2))] = v;
    }
    __syncthreads();

    int arow = rg * 32 + l31;
    const char* abase = (const char*)sA + arow * 256;
    int swz = (arow & 15) << 4;
    f32x16 acc[2];
#pragma unroll
    for (int t = 0; t < 2; t++) {
#pragma unroll
      for (int r = 0; r < 16; r++) acc[t][r] = 0.f;
    }
#pragma unroll
    for (int kk = 0; kk < 8; kk++) {
      bf16x8 a = *(const bf16x8*)(abase + ((kk * 32 + h * 16) ^ swz));
      acc[0] = __builtin_amdgcn_mfma_f32_32x32x16_bf16(a, wf[0][kk], acc[0], 0, 0, 0);
      acc[1] = __builtin_amdgcn_mfma_f32_32x32x16_bf16(a, wf[1][kk], acc[1], 0, 0, 0);
    }
#pragma unroll
    for (int r = 0; r < 16; r++) {
      int drow = (r & 3) + 8 * (r >> 2) + 4 * h;
      int n = row0 + rg * 32 + drow;
      if (n < N) {
        float v0 = acc[0][r] + bcol[0];
        float v1 = acc[1][r] + bcol[1];
        outp[(size_t)n * 64 + ch * 32 + l31] = f2bf_pack(v0, v1);
      }
    }
  }
}

// ---------------- fused edge MLP: dst-sorted order + full gather prefetch, 3 waves/EU ----------------
// NOTE (measured R7/R9/R13): any cross-phase register state (deeper prefetch, 4-waves/EU)
// converts to scratch spill at this kernel's 84-reg/3-wave operating point. This config is
// the measured optimum: just-in-time gathers, all 32 issued before use, no held state.
__global__ __launch_bounds__(256, 3) void k_edge_mlp(
    const unsigned* __restrict__ a_s, const unsigned* __restrict__ a_d,
    const float* __restrict__ eattr, const int* __restrict__ slots,
    const int2* __restrict__ epair, const float* __restrict__ We,
    const float* __restrict__ Wm2, const float* __restrict__ bm2,
    const float* __restrict__ Wm3, const float* __restrict__ bm3,
    float* __restrict__ out, int E) {
  __shared__ unsigned sZ1[64 * 64];  // 64 rows x 128 bf16, XOR-swizzled
  __shared__ float sEa[64][5];
  __shared__ int sSrc[64], sDst[64], sEid[64];
  __shared__ float sP[64][2];

  int tid = threadIdx.x;
  int wv = tid >> 6;
  int lane = tid & 63;
  int rg = wv >> 1;
  int ch = wv & 1;
  int l31 = lane & 31;
  int h = lane >> 5;

  bf16x8 bfr[2][8];
#pragma unroll
  for (int t = 0; t < 2; t++) {
    int col = ch * 64 + t * 32 + l31;
#pragma unroll
    for (int kk = 0; kk < 8; kk++) {
      int kb = kk * 16 + h * 8;
      bf16x8 v;
#pragma unroll
      for (int u = 0; u < 8; u++) v[u] = f2bf(Wm2[(kb + u) * 128 + col]);
      bfr[t][kk] = v;
    }
  }
  float wm3c[2], bm2c[2];
#pragma unroll
  for (int t = 0; t < 2; t++) {
    int col = ch * 64 + t * 32 + l31;
    wm3c[t] = Wm3[col];
    bm2c[t] = bm2[col];
  }
  float bm3v = bm3[0];
  float2 we[5];
#pragma unroll
  for (int j = 0; j < 5; j++) we[j] = *(const float2*)(We + j * 128 + 2 * lane);

  int ntiles = (E + 63) >> 6;
  for (int tile = blockIdx.x; tile < ntiles; tile += gridDim.x) {
    __syncthreads();
    int p0 = tile << 6;
    if (tid < 64) {
      int p = p0 + tid;
      int2 ed = (p < E) ? epair[p] : make_int2(0, 0);
      sSrc[tid] = (p < E) ? slots[p] : 0;
      sDst[tid] = ed.y;
      sEid[tid] = ed.x;
    }
    for (int idx = tid; idx < 320; idx += 256) {
      int r = idx / 5, j = idx - r * 5;
      int p = p0 + r;
      int e = (p < E) ? epair[p].x : 0;
      sEa[r][j] = (p < E) ? eattr[(size_t)e * 5 + j] : 0.f;
    }
    __syncthreads();

    // Phase A: issue ALL 32 gathers first (static-indexed regs), then compute
    unsigned ua[16], ud[16];
#pragma unroll
    for (int i = 0; i < 16; i++) {
      int r = wv * 16 + i;
      ua[i] = a_s[(size_t)sSrc[r] * 64 + lane];
      ud[i] = a_d[(size_t)sDst[r] * 64 + lane];
    }
#pragma unroll
    for (int i = 0; i < 16; i++) {
      int r = wv * 16 + i;
      float v0 = bflo(ua[i]) + bflo(ud[i]);
      float v1 = bfhi(ua[i]) + bfhi(ud[i]);
#pragma unroll
      for (int j = 0; j < 5; j++) {
        float ea = sEa[r][j];
        v0 = fmaf(ea, we[j].x, v0);
        v1 = fmaf(ea, we[j].y, v1);
      }
      v0 = fmaxf(v0, 0.f);
      v1 = fmaxf(v1, 0.f);
      sZ1[r * 64 + (lane ^ ((r & 15) << 2))] = f2bf_pack(v0, v1);
    }
    __syncthreads();

    // Phase B: C[32 rows][64 cols] via mfma_f32_32x32x16_bf16
    int arow = rg * 32 + l31;
    const char* abase = (const char*)sZ1 + arow * 256;
    int swz = (arow & 15) << 4;
    float p16[16];
#pragma unroll
    for (int r = 0; r < 16; r++) p16[r] = 0.f;
#pragma unroll
    for (int t = 0; t < 2; t++) {
      f32x16 acc;
#pragma unroll
      for (int r = 0; r < 16; r++) acc[r] = 0.f;
#pragma unroll
      for (int kk = 0; kk < 8; kk++) {
        bf16x8 a = *(const bf16x8*)(abase + ((kk * 32 + h * 16) ^ swz));
        acc = __builtin_amdgcn_mfma_f32_32x32x16_bf16(a, bfr[t][kk], acc, 0, 0, 0);
      }
#pragma unroll
      for (int r = 0; r < 16; r++) {
        float z2 = fmaxf(acc[r] + bm2c[t], 0.f);
        p16[r] = fmaf(z2, wm3c[t], p16[r]);
      }
    }
#pragma unroll
    for (int r = 0; r < 16; r++) {
      float p = p16[r];
#pragma unroll
      for (int off = 16; off >= 1; off >>= 1) p += __shfl_xor(p, off, 32);
      if (l31 == 0) {
        int row = (r & 3) + 8 * (r >> 2) + 4 * h;
        sP[rg * 32 + row][ch] = p;
      }
    }
    __syncthreads();
    if (tid < 64) {
      int p = p0 + tid;
      if (p < E) {
        float pv = sP[tid][0] + sP[tid][1] + bm3v;
        out[sEid[tid]] = 1.f / (1.f + __expf(-pv));
      }
    }
  }
}

// ---------------- launch ----------------
extern "C" void kernel_launch(void* const* d_in, const int* in_sizes, int n_in,
                              void* d_out, int out_size, void* d_ws, size_t ws_size,
                              hipStream_t stream) {
  const float* x = (const float*)d_in[0];
  const float* eattr = (const float*)d_in[1];
  const float* W1 = (const float*)d_in[2];
  const float* b1 = (const float*)d_in[3];
  const float* W2 = (const float*)d_in[4];
  const float* b2 = (const float*)d_in[5];
  const float* Wm1 = (const float*)d_in[6];
  const float* bm1 = (const float*)d_in[7];
  const float* Wm2 = (const float*)d_in[8];
  const float* bm2 = (const float*)d_in[9];
  const float* Wm3 = (const float*)d_in[10];
  const float* bm3 = (const float*)d_in[11];
  const int* ei = (const int*)d_in[12];
  int N = in_sizes[0] / 4;
  int E = in_sizes[12] / 2;
  const int* src = ei;
  const int* dst = ei + E;
  float* out = (float*)d_out;

  size_t npad = (size_t)((N + 63) & ~63);
  float* dinv = (float*)d_ws;
  float4* xs = (float4*)(dinv + npad);          // npad float4
  unsigned* U1 = (unsigned*)(xs + npad);        // ts2
  unsigned* U2 = U1 + (size_t)N * 64;           // h1, later a_s
  unsigned* U3 = U2 + (size_t)N * 64;           // h2
  unsigned* U4 = U3 + (size_t)N * 64;           // a_d
  int* degi = (int*)(U4 + (size_t)N * 64);
  int* rowoff = degi + npad;
  int* cursor = rowoff + npad;
  int* bsum = cursor + npad;  // 256 slots
  int* slots = bsum + 256;
  int2* epair = (int2*)(slots + ((E + 1) & ~1));

  int gN = (N + TPB - 1) / TPB;
  int gE = (E + TPB - 1) / TPB;
  int gN16 = (N * 16 + TPB - 1) / TPB;
  int nb1 = (N + SCAN_CHUNK - 1) / SCAN_CHUNK;

  // CSR build (dst-sorted adjacency) + dinv + xs
  k_zero_int<<<gN, TPB, 0, stream>>>(degi, N);
  k_hist<<<gE, TPB, 0, stream>>>(dst, degi, E);
  k_scan_local<<<nb1, SCAN_T, 0, stream>>>(degi, rowoff, bsum, dinv, (const float4*)x, xs, N);
  k_scan_block<<<1, 64, 0, stream>>>(bsum, nb1);
  k_scan_add<<<gN, TPB, 0, stream>>>(rowoff, bsum, cursor, N);
  k_fill_slots<<<gE, TPB, 0, stream>>>(src, dst, cursor, slots, epair, E);

  // GCN layer 1 (fused transform+aggregate via linearity): h1 in U2
  k_agg1<<<2048, TPB, 0, stream>>>(xs, rowoff, degi, slots, dinv, W1, b1, U2, N);

  // GCN layer 2: ts2 = dinv*(h1@W2) (U1) -> h2 (U3)
  k_gemm_bf<false, true><<<512, TPB, 0, stream>>>(U2, W2, nullptr, dinv, U1, N);
  k_agg<false><<<gN16, TPB, 0, stream>>>(U1, rowoff, degi, slots, dinv, b2, U3, N);

  // Edge classifier: a_s (U2), a_d (U4) in one fused kernel
  k_gemm_dual<<<512, 512, 0, stream>>>(U3, Wm1, bm1, U2, U4, N);
  k_edge_mlp<<<2048, TPB, 0, stream>>>(U2, U4, eattr, slots, epair,
                                       Wm1 + 256 * 128, Wm2, bm2, Wm3, bm3, out, E);
}